// Round 10
// baseline (35.232 us; speedup 1.0000x reference)
//
#include <hip/hip_runtime.h>
#include <cfloat>
#include <climits>

#define B_   8
#define N1_  1024
#define N2_  4096
#define C_   256
#define QPT  2      // queries per thread
#define QPB  16     // queries per block (8 slots x 2)

typedef float vf2 __attribute__((ext_vector_type(2)));

__device__ __forceinline__ unsigned umin_(unsigned a, unsigned b) { return a < b ? a : b; }
__device__ __forceinline__ unsigned umax_(unsigned a, unsigned b) { return a > b ? a : b; }

// Sorted-quad insert of packed key k, total u32 order. Invariant k0<=k1<=k2<=k3.
#define KINS4(k, k0, k1, k2, k3) do {                 \
    unsigned _n1 = umax_(k0, umin_((k), k1));         \
    unsigned _n2 = umax_(k1, umin_((k), k2));         \
    unsigned _n3 = umax_(k2, umin_((k), k3));         \
    k0 = umin_((k), k0);  k1 = _n1;  k2 = _n2;  k3 = _n3; \
} while (0)

// ---------------------------------------------------------------------------
// Kernel 1 (v7): 3-NN, truncated-key top-4 scan + EXACT rescue (validated in
// R9), re-tuned for occupancy: QPT=2 -> grid 2048 blocks (8 blocks/CU, 32
// waves/CU = 100%), __launch_bounds__(256,8) caps VGPR at 64.
// - scan key = (bits(max(dd,0)) & ~1023) | n  (u32 order == (trunc dist, idx))
// - top-4 absorbs trunc-ties at the 3|4 boundary; finalize recomputes the 4
//   dists EXACTLY (reference bit order), exact (d,idx) sort4, take 3.
// ---------------------------------------------------------------------------
__global__ __launch_bounds__(256, 8) void knn_kernel(
    const float* __restrict__ p1, const float* __restrict__ p2,
    int4* __restrict__ wsi, float4* __restrict__ wsw) {
#pragma clang fp contract(off)
    __shared__ float4 pts[N1_];   // (2x, 2y, 2z, |p1|^2): 16 KB

    const int tid   = threadIdx.x;
    const int b     = blockIdx.x >> 8;     // 256 query-tiles per batch
    const int mtile = blockIdx.x & 255;
    const int slice = tid & 31;            // candidate slice
    const int slot  = tid >> 5;            // 0..7 query slot
    const int mbase = mtile * QPB + slot * QPT;

    // This thread's 2 queries: 6 floats, 8B-aligned -> 3 float2 loads
    // (all 32 lanes of a slot read the same 24B; cache broadcast).
    const float2* P2 = reinterpret_cast<const float2*>(
        p2 + ((size_t)b * N2_ + mbase) * 3);
    const float2 g0 = P2[0], g1 = P2[1], g2 = P2[2];

    // Stage coarse points {2x,2y,2z,|p1|^2} (pre-double exact under RN).
    for (int j = tid; j < N1_; j += 256) {
        float x = p1[((size_t)b * N1_ + j) * 3 + 0];
        float y = p1[((size_t)b * N1_ + j) * 3 + 1];
        float z = p1[((size_t)b * N1_ + j) * 3 + 2];
        float s1 = __fadd_rn(__fadd_rn(__fmul_rn(x, x), __fmul_rn(y, y)),
                             __fmul_rn(z, z));
        pts[j] = make_float4(x + x, y + y, z + z, s1);
    }

    const float x0 = g0.x, y0 = g0.y, z0 = g1.x;
    const float x1q = g1.y, y1q = g2.x, z1q = g2.y;
    const vf2 xA = {x0, x1q};
    const vf2 yA = {y0, y1q};
    const vf2 zA = {z0, z1q};
    const vf2 sA = (xA * xA + yA * yA) + zA * zA;   // (xx+yy)+zz, ref order

    __syncthreads();

    unsigned k00 = UINT_MAX, k01 = UINT_MAX, k02 = UINT_MAX, k03 = UINT_MAX;
    unsigned k10 = UINT_MAX, k11 = UINT_MAX, k12 = UINT_MAX, k13 = UINT_MAX;

#pragma unroll 4
    for (int j = 0; j < N1_ / 32; ++j) {
        const int n = j * 32 + slice;
        const float4 c = pts[n];
        const vf2 cx = {c.x, c.x}, cy = {c.y, c.y};
        const vf2 cz = {c.z, c.z}, cw = {c.w, c.w};
        // dd = (s2 - dot2) + s1, dot2 = (x2*2x + y2*2y) + z2*2z == 2*dot
        const vf2 dA = (sA - ((xA * cx + yA * cy) + zA * cz)) + cw;
        const unsigned un = (unsigned)n;
        const unsigned q0 = (__float_as_uint(fmaxf(dA.x, 0.f)) & 0xFFFFFC00u) | un;
        const unsigned q1 = (__float_as_uint(fmaxf(dA.y, 0.f)) & 0xFFFFFC00u) | un;
        KINS4(q0, k00, k01, k02, k03);
        KINS4(q1, k10, k11, k12, k13);
    }

    // Butterfly-merge the 32 slices (u32 key order == (trunc dist, idx) lex).
#pragma unroll
    for (int mask = 1; mask < 32; mask <<= 1) {
        unsigned p0, p1_, p2_, p3_;
        p0  = (unsigned)__shfl_xor((int)k00, mask, 32);
        p1_ = (unsigned)__shfl_xor((int)k01, mask, 32);
        p2_ = (unsigned)__shfl_xor((int)k02, mask, 32);
        p3_ = (unsigned)__shfl_xor((int)k03, mask, 32);
        KINS4(p0, k00, k01, k02, k03); KINS4(p1_, k00, k01, k02, k03);
        KINS4(p2_, k00, k01, k02, k03); KINS4(p3_, k00, k01, k02, k03);
        p0  = (unsigned)__shfl_xor((int)k10, mask, 32);
        p1_ = (unsigned)__shfl_xor((int)k11, mask, 32);
        p2_ = (unsigned)__shfl_xor((int)k12, mask, 32);
        p3_ = (unsigned)__shfl_xor((int)k13, mask, 32);
        KINS4(p0, k10, k11, k12, k13); KINS4(p1_, k10, k11, k12, k13);
        KINS4(p2_, k10, k11, k12, k13); KINS4(p3_, k10, k11, k12, k13);
    }

    // Slices 0..1 finalize query (mbase + slice): exact rescue of 4 -> 3.
    if (slice < QPT) {
        const unsigned a0 = slice == 0 ? k00 : k10;
        const unsigned a1 = slice == 0 ? k01 : k11;
        const unsigned a2 = slice == 0 ? k02 : k12;
        const unsigned a3 = slice == 0 ? k03 : k13;
        const float qx = slice == 0 ? x0 : x1q;
        const float qy = slice == 0 ? y0 : y1q;
        const float qz = slice == 0 ? z0 : z1q;
        const float qs = slice == 0 ? sA.x : sA.y;

        int   ix[4];
        float dx[4];
#pragma unroll
        for (int k = 0; k < 4; ++k) {
            const unsigned a = k == 0 ? a0 : k == 1 ? a1 : k == 2 ? a2 : a3;
            const int n = (int)(a & 1023u);
            const float4 c = pts[n];
            // EXACT reference arithmetic: dd = (s2 - dot2) + s1
            dx[k] = __fadd_rn(__fsub_rn(qs,
                __fadd_rn(__fadd_rn(__fmul_rn(qx, c.x), __fmul_rn(qy, c.y)),
                          __fmul_rn(qz, c.z))), c.w);
            ix[k] = n;
        }
        // Exact lexicographic (d, idx) sort-4 network: (0,1)(2,3)(0,2)(1,3)(1,2)
#define CSWAP(a, b) do {                                            \
        bool sw = (dx[b] < dx[a]) || (dx[b] == dx[a] && ix[b] < ix[a]); \
        float td = sw ? dx[b] : dx[a]; dx[b] = sw ? dx[a] : dx[b]; dx[a] = td; \
        int   ti = sw ? ix[b] : ix[a]; ix[b] = sw ? ix[a] : ix[b]; ix[a] = ti; \
    } while (0)
        CSWAP(0, 1); CSWAP(2, 3); CSWAP(0, 2); CSWAP(1, 3); CSWAP(1, 2);
#undef CSWAP

        const float r0 = 1.0f / __fadd_rn(dx[0], 1e-8f);
        const float r1 = 1.0f / __fadd_rn(dx[1], 1e-8f);
        const float r2 = 1.0f / __fadd_rn(dx[2], 1e-8f);
        const float s  = __fadd_rn(__fadd_rn(r0, r1), r2);
        const size_t o = (size_t)b * N2_ + mbase + slice;
        wsi[o] = make_int4(ix[0], ix[1], ix[2], 0);
        wsw[o] = make_float4(r0 / s, r1 / s, r2 / s, 0.0f);
    }
}

// ---------------------------------------------------------------------------
// Kernel 2 (v4): gather + blend — byte-exact round-6 version (control).
// ---------------------------------------------------------------------------

__global__ __launch_bounds__(256) void blend_kernel(
    const float* __restrict__ x1, const int4* __restrict__ wsi,
    const float4* __restrict__ wsw, float* __restrict__ out) {
    __shared__ float4 L4[N1_];   // 16 KB, XOR-swizzled channel-interleaved

    int bid = blockIdx.x;
    const int mhalf = bid & 1;
    const int ct    = (bid >> 1) & 63;   // 64 channel tiles of 4
    const int b     = bid >> 7;
    const int tid   = threadIdx.x;

    // Prefetch idx/weights for all 8 m-iterations.
    const size_t wbase = (size_t)b * N2_ + (size_t)mhalf * 2048;
    int4   id[8];
    float4 w[8];
#pragma unroll
    for (int mb = 0; mb < 8; ++mb) {
        id[mb] = wsi[wbase + mb * 256 + tid];
        w[mb]  = wsw[wbase + mb * 256 + tid];
    }

    // Stage 4 channels, register-transposed into interleaved LDS.
    const float* src = x1 + ((size_t)b * C_ + (size_t)ct * 4) * N1_;
    float4 v[4];
#pragma unroll
    for (int c = 0; c < 4; ++c)
        v[c] = reinterpret_cast<const float4*>(src + (size_t)c * N1_)[tid];
#pragma unroll
    for (int e = 0; e < 4; ++e) {
        const int n = 4 * tid + e;
        L4[n ^ ((n >> 3) & 7)] = make_float4((&v[0].x)[e], (&v[1].x)[e],
                                             (&v[2].x)[e], (&v[3].x)[e]);
    }
    __syncthreads();

    const size_t obase = ((size_t)b * C_ + (size_t)ct * 4) * N2_;
#pragma unroll
    for (int mb = 0; mb < 8; ++mb) {
        const int m = mhalf * 2048 + mb * 256 + tid;
        const int na = id[mb].x, nb = id[mb].y, nc = id[mb].z;
        const float4 A  = L4[na ^ ((na >> 3) & 7)];
        const float4 Bv = L4[nb ^ ((nb >> 3) & 7)];
        const float4 Cv = L4[nc ^ ((nc >> 3) & 7)];
        const float wx = w[mb].x, wy = w[mb].y, wz = w[mb].z;
#pragma unroll
        for (int r = 0; r < 4; ++r) {
            float acc = __fadd_rn(__fadd_rn(__fmul_rn((&A.x)[r],  wx),
                                            __fmul_rn((&Bv.x)[r], wy)),
                                  __fmul_rn((&Cv.x)[r], wz));
            __builtin_nontemporal_store(acc, &out[obase + (size_t)r * N2_ + m]);
        }
    }
}

extern "C" void kernel_launch(void* const* d_in, const int* in_sizes, int n_in,
                              void* d_out, int out_size, void* d_ws, size_t ws_size,
                              hipStream_t stream) {
    const float* p1 = (const float*)d_in[0];   // [B, N1, 3]
    const float* x1 = (const float*)d_in[1];   // [B, C, N1]
    const float* p2 = (const float*)d_in[2];   // [B, N2, 3]
    float* out = (float*)d_out;                // [B, C, N2]

    int4*   wsi = (int4*)d_ws;
    float4* wsw = (float4*)((char*)d_ws + (size_t)B_ * N2_ * sizeof(int4));

    knn_kernel<<<B_ * (N2_ / QPB), 256, 0, stream>>>(p1, p2, wsi, wsw);
    blend_kernel<<<B_ * (C_ / 4) * 2, 256, 0, stream>>>(x1, wsi, wsw, out);
}